// Round 7
// baseline (160.555 us; speedup 1.0000x reference)
//
#include <hip/hip_runtime.h>
#include <hip/hip_bf16.h>

// QuantumKANLayer: S = [cos|sin features](32768x4096) @ W(4096x256), bf16 MFMA.
// R6: per-CU cycle-balanced design.
//   - MFMA 32x32x16, wave tile 64x64 (2M x 2N): each B-frag reused by 2 MFMAs
//     -> B-LDS-read = 512B/MFMA (32k cyc/CU < 66k MFMA).
//   - A computed in-lane (2 Chebyshev chains per lane per k-slice, ~40k cyc).
//   - B staged to LDS via global_load_lds (un-sinkable async DMA), issued a
//     full group early (T14): barrier drain is free.
//   - block 512 thr = 8 waves (2Mw x 4Nw), BM=128, grid 256 = 1 block/CU.
//
// k-slot semantics (A and B agree): for k-slice i, slot h*8+e <->
// (h ? sin : cos)((e+1) * x[row][i]).

#define NGRP 64          // 64 groups x 4 i = 256 i; 64 k per group

typedef __attribute__((ext_vector_type(8)))  short short8;
typedef __attribute__((ext_vector_type(16))) float f32x16;

typedef __attribute__((address_space(3))) void lds_void;
typedef const __attribute__((address_space(1))) void gbl_void;

static __device__ __forceinline__ unsigned short f2bf(float f) {
    union { float f; unsigned u; } v; v.f = f;
    unsigned r = v.u + 0x7fff + ((v.u >> 16) & 1);   // RNE
    return (unsigned short)(r >> 16);
}

// ---- pack W^T fragment-major for 32x32x16 B-frags -------------------------
// flat idx = (i*8 + cg)*64 + l,  16B per idx.
// lane l: col j = cg*32 + (l&31), h = l>>5,
//         val[e] = (h ? coef_b : coef_a)[j][i][e]
__global__ __launch_bounds__(256) void pack_w_kernel(
        const float* __restrict__ ca, const float* __restrict__ cb,
        unsigned short* __restrict__ wt) {
    int idx = blockIdx.x * 256 + threadIdx.x;   // 131072
    int l  = idx & 63;
    int cg = (idx >> 6) & 7;
    int i  = idx >> 9;
    int j  = cg * 32 + (l & 31);
    const float* src = ((l >> 5) ? cb : ca) + ((size_t)j * 256 + i) * 8;
    float4 v0 = ((const float4*)src)[0];
    float4 v1 = ((const float4*)src)[1];
    alignas(16) unsigned short o[8];
    o[0] = f2bf(v0.x); o[1] = f2bf(v0.y); o[2] = f2bf(v0.z); o[3] = f2bf(v0.w);
    o[4] = f2bf(v1.x); o[5] = f2bf(v1.y); o[6] = f2bf(v1.z); o[7] = f2bf(v1.w);
    *(short8*)(wt + (size_t)idx * 8) = *(short8*)o;
}

// ---- fused feature-gen + GEMM --------------------------------------------
// grid 256, block 512 = 8 waves (2Mw x 4Nw). Wave (wm,wn): rows
// bm0 + wm*64 .. +63 (2 frags), cols wn*64 .. +63 (2 frags).
// B group = 4 k-slices = 32 KB, double-buffered (64 KB LDS).
template<bool PACKED>
__global__ __launch_bounds__(512, 2) void kan_gemm(
        const float* __restrict__ x,
        const unsigned short* __restrict__ bwt,
        const float* __restrict__ ca, const float* __restrict__ cb,
        float* __restrict__ out) {
    __shared__ __align__(16) char Blds[2][32768];

    const int tid   = threadIdx.x;
    const int l     = tid & 63;
    const int w     = tid >> 6;       // 0..7
    const int lrow  = l & 31;
    const int lhalf = l >> 5;
    const int wm    = w & 1;          // 2 M-waves
    const int wn    = w >> 1;         // 4 N-waves
    const int bm0   = blockIdx.x * 128;
    const int cg0   = wn * 2;

    f32x16 acc[2][2];                 // [m][n], 64 VGPR
#pragma unroll
    for (int m = 0; m < 2; ++m)
#pragma unroll
        for (int n = 0; n < 2; ++n)
#pragma unroll
            for (int r = 0; r < 16; ++r) acc[m][n][r] = 0.0f;

    // x pointers for this lane's two rows (m=0,1)
    const float* xr0 = x + (size_t)(bm0 + wm * 64 + lrow) * 256;
    const float* xr1 = xr0 + 32 * 256;
    const float p2init = lhalf ? 0.0f : 1.0f;

    // fallback staging registers
    short8 sreg[4];

    auto stage_issue = [&](int buf, int g) {
        if (PACKED) {
            const char* src = (const char*)bwt + (size_t)g * 32768;
            char* dstb = Blds[buf];
#pragma unroll
            for (int p = 0; p < 4; ++p) {
                const int go = p * 512 + (w << 6);        // wave-uniform granule
                __builtin_amdgcn_global_load_lds(
                    (gbl_void*)(src + (size_t)(go + l) * 16),
                    (lds_void*)(dstb + (size_t)go * 16), 16, 0, 0);
            }
        } else {
#pragma unroll
            for (int p = 0; p < 4; ++p) {
                const int G  = p * 512 + tid;
                const int lg = G & 63;
                const int cg = (G >> 6) & 7;
                const int ii = G >> 9;
                const int j  = cg * 32 + (lg & 31);
                const int i  = g * 4 + ii;
                const float* s = ((lg >> 5) ? cb : ca)
                               + ((size_t)j * 256 + i) * 8;
                float4 v0 = ((const float4*)s)[0];
                float4 v1 = ((const float4*)s)[1];
                alignas(16) unsigned short o[8];
                o[0] = f2bf(v0.x); o[1] = f2bf(v0.y);
                o[2] = f2bf(v0.z); o[3] = f2bf(v0.w);
                o[4] = f2bf(v1.x); o[5] = f2bf(v1.y);
                o[6] = f2bf(v1.z); o[7] = f2bf(v1.w);
                sreg[p] = *(short8*)o;
            }
        }
    };
    auto stage_write = [&](int buf) {
        if (!PACKED) {
#pragma unroll
            for (int p = 0; p < 4; ++p)
                *(short8*)(Blds[buf] + (size_t)(p * 512 + tid) * 16) = sreg[p];
        }
    };

    // chain: 8 harmonics of (lhalf ? sin : cos) via Chebyshev recurrence
    auto chain = [&](float xv) -> short8 {
        float s1, c1;
        __sincosf(xv, &s1, &c1);
        float p1 = lhalf ? s1 : c1;
        float p2 = p2init;
        alignas(16) __hip_bfloat16 h[8];
        h[0] = __float2bfloat16(p1);
        const float tc = c1 + c1;
#pragma unroll
        for (int k = 1; k < 8; ++k) {
            const float pn = __builtin_fmaf(tc, p1, -p2);
            p2 = p1; p1 = pn;
            h[k] = __float2bfloat16(pn);
        }
        return *(const short8*)h;
    };

    // prologue: stage group 0, then barrier (drains the DMA)
    stage_issue(0, 0);
    stage_write(0);
    float4 xa0 = *(const float4*)(xr0);
    float4 xa1 = *(const float4*)(xr1);
    __syncthreads();

    // per-thread LDS read base (cg0 frag pair), reach everything via imm offs
    const char* bbase = Blds[0] + (size_t)(cg0 * 64 + l) * 16;

#pragma unroll 1
    for (int g = 0; g < NGRP; ++g) {
        const int buf = g & 1;

        if (g + 1 < NGRP) stage_issue(buf ^ 1, g + 1);   // async, lands under MFMA
        float4 xn0 = xa0, xn1 = xa1;
        if (g + 1 < NGRP) {
            xn0 = *(const float4*)(xr0 + (size_t)(g + 1) * 4);
            xn1 = *(const float4*)(xr1 + (size_t)(g + 1) * 4);
        }

#pragma unroll
        for (int ii = 0; ii < 4; ++ii) {
            const short8 af0 = chain(xa0[ii]);
            const short8 af1 = chain(xa1[ii]);
            const short8 b0 = *(const short8*)(bbase + buf * 32768 + ii * 8192);
            const short8 b1 = *(const short8*)(bbase + buf * 32768 + ii * 8192 + 1024);

            __builtin_amdgcn_s_setprio(1);
            acc[0][0] = __builtin_amdgcn_mfma_f32_32x32x16_bf16(
                af0, b0, acc[0][0], 0, 0, 0);
            acc[0][1] = __builtin_amdgcn_mfma_f32_32x32x16_bf16(
                af0, b1, acc[0][1], 0, 0, 0);
            acc[1][0] = __builtin_amdgcn_mfma_f32_32x32x16_bf16(
                af1, b0, acc[1][0], 0, 0, 0);
            acc[1][1] = __builtin_amdgcn_mfma_f32_32x32x16_bf16(
                af1, b1, acc[1][1], 0, 0, 0);
            __builtin_amdgcn_s_setprio(0);
        }

        if (g + 1 < NGRP) stage_write(buf ^ 1);
        __syncthreads();
        xa0 = xn0; xa1 = xn1;
    }

    // epilogue: 32x32 C/D: col = lane&31, row = (r&3) + 8*(r>>2) + 4*lhalf
#pragma unroll
    for (int m = 0; m < 2; ++m)
#pragma unroll
        for (int n = 0; n < 2; ++n)
#pragma unroll
            for (int r = 0; r < 16; ++r) {
                const int orow = bm0 + wm * 64 + m * 32
                               + (r & 3) + 8 * (r >> 2) + 4 * lhalf;
                const int ocol = wn * 64 + n * 32 + lrow;
                out[(size_t)orow * 256 + ocol] = acc[m][n][r];
            }
}

extern "C" void kernel_launch(void* const* d_in, const int* in_sizes, int n_in,
                              void* d_out, int out_size, void* d_ws, size_t ws_size,
                              hipStream_t stream) {
    const float* x  = (const float*)d_in[0];
    const float* ca = (const float*)d_in[1];
    const float* cb = (const float*)d_in[2];
    float* out = (float*)d_out;

    const size_t wt_bytes = (size_t)131072 * 16;   // 2 MiB

    if (ws_size >= wt_bytes) {
        unsigned short* wt = (unsigned short*)d_ws;
        pack_w_kernel<<<512, 256, 0, stream>>>(ca, cb, wt);
        kan_gemm<true><<<256, 512, 0, stream>>>(x, wt, ca, cb, out);
    } else {
        kan_gemm<false><<<256, 512, 0, stream>>>(x, nullptr, ca, cb, out);
    }
}

// Round 8
// 91.670 us; speedup vs baseline: 1.7514x; 1.7514x over previous
//
#include <hip/hip_runtime.h>
#include <hip/hip_bf16.h>

// QuantumKANLayer: S = [cos|sin features](32768x4096) @ W(4096x256), bf16 MFMA.
// R7: wave = 64 rows x 128 cols (acc[2][4]): in-lane Chebyshev chains amortized
//     over 4 col-frags (VALU = 28% of MFMA budget). Two-slot software pipeline
//     (af/b for ii+1 computed during MFMAs of ii) breaks the serial-latency
//     chain that killed R4-R6. 8 waves = 2(k-split) x 4(M); BM=256, BN=128,
//     grid 256. B staged 32KB/group via global_load_lds, double-buffered.
//     K-split halves combined through LDS in the epilogue.
//
// k-slot semantics: for k-slice i, slot h*8+e <-> (h?sin:cos)((e+1)*x[row][i]).

#define NGRP 32          // per k-half: 128 i = 32 groups x 4 i

typedef __attribute__((ext_vector_type(8)))  short short8;
typedef __attribute__((ext_vector_type(16))) float f32x16;

typedef __attribute__((address_space(3))) void lds_void;
typedef const __attribute__((address_space(1))) void gbl_void;

static __device__ __forceinline__ unsigned short f2bf(float f) {
    union { float f; unsigned u; } v; v.f = f;
    unsigned r = v.u + 0x7fff + ((v.u >> 16) & 1);   // RNE
    return (unsigned short)(r >> 16);
}

// ---- pack W^T fragment-major for 32x32x16 B-frags -------------------------
// granule (i, cg) at wt + ((i*8+cg)*64+l)*8 shorts; lane l (16B):
// col j = cg*32 + (l&31), h = l>>5, val[e] = (h ? coef_b : coef_a)[j][i][e]
__global__ __launch_bounds__(256) void pack_w_kernel(
        const float* __restrict__ ca, const float* __restrict__ cb,
        unsigned short* __restrict__ wt) {
    int idx = blockIdx.x * 256 + threadIdx.x;   // 131072
    int l  = idx & 63;
    int cg = (idx >> 6) & 7;
    int i  = idx >> 9;
    int j  = cg * 32 + (l & 31);
    const float* src = ((l >> 5) ? cb : ca) + ((size_t)j * 256 + i) * 8;
    float4 v0 = ((const float4*)src)[0];
    float4 v1 = ((const float4*)src)[1];
    alignas(16) unsigned short o[8];
    o[0] = f2bf(v0.x); o[1] = f2bf(v0.y); o[2] = f2bf(v0.z); o[3] = f2bf(v0.w);
    o[4] = f2bf(v1.x); o[5] = f2bf(v1.y); o[6] = f2bf(v1.z); o[7] = f2bf(v1.w);
    *(short8*)(wt + (size_t)idx * 8) = *(short8*)o;
}

// ---- fused feature-gen + GEMM --------------------------------------------
template<bool PACKED>
__global__ __launch_bounds__(512, 2) void kan_gemm(
        const float* __restrict__ x,
        const unsigned short* __restrict__ bwt,
        const float* __restrict__ ca, const float* __restrict__ cb,
        float* __restrict__ out) {
    __shared__ __align__(16) char Blds[2][32768];

    const int tid   = threadIdx.x;
    const int l     = tid & 63;
    const int w     = tid >> 6;       // 0..7
    const int lrow  = l & 31;
    const int lhalf = l >> 5;
    const int kh    = w >> 2;         // k-split half
    const int wm    = w & 3;          // 4 M-waves
    const int rb    = blockIdx.x >> 1;
    const int ch    = blockIdx.x & 1;

    f32x16 acc0[4], acc1[4];          // [cf] for rowfrag 0 / 1
#pragma unroll
    for (int cf = 0; cf < 4; ++cf)
#pragma unroll
        for (int r = 0; r < 16; ++r) { acc0[cf][r] = 0.0f; acc1[cf][r] = 0.0f; }

    // x pointers: this lane's two rows, this k-half's i-range
    const float* xp0 = x + ((size_t)(rb * 256 + wm * 64 + lrow)) * 256 + kh * 128;
    const float* xp1 = xp0 + 32 * 256;
    const float p2init = lhalf ? 0.0f : 1.0f;

    // LDS read base: granule (kh, ii, cf) at kh*16K + ii*4K + cf*1K
    const char* bbase = (const char*)&Blds[0][0] + kh * 16384 + l * 16;

    short8 sreg[4];   // fallback staging

    auto stage_issue = [&](int buf, int g) {
#pragma unroll
        for (int q = 0; q < 4; ++q) {
            const int p    = w * 4 + q;              // granule 0..31
            const int kh_s = p >> 4;
            const int ii_s = (p >> 2) & 3;
            const int cf_s = p & 3;
            const int i_s  = kh_s * 128 + g * 4 + ii_s;
            const int cg   = ch * 4 + cf_s;
            if (PACKED) {
                const char* src = (const char*)bwt
                                + ((size_t)(i_s * 8 + cg) * 64 + l) * 16;
                char* dst = (char*)&Blds[0][0] + buf * 32768 + p * 1024;
                __builtin_amdgcn_global_load_lds((gbl_void*)src, (lds_void*)dst,
                                                 16, 0, 0);
            } else {
                const int j = cg * 32 + (l & 31);
                const float* s = ((l >> 5) ? cb : ca)
                               + ((size_t)j * 256 + i_s) * 8;
                float4 v0 = ((const float4*)s)[0];
                float4 v1 = ((const float4*)s)[1];
                alignas(16) unsigned short o[8];
                o[0] = f2bf(v0.x); o[1] = f2bf(v0.y);
                o[2] = f2bf(v0.z); o[3] = f2bf(v0.w);
                o[4] = f2bf(v1.x); o[5] = f2bf(v1.y);
                o[6] = f2bf(v1.z); o[7] = f2bf(v1.w);
                sreg[q] = *(short8*)o;
            }
        }
    };
    auto stage_write = [&](int buf) {
        if (!PACKED) {
#pragma unroll
            for (int q = 0; q < 4; ++q) {
                const int p = w * 4 + q;
                *(short8*)((char*)&Blds[0][0] + buf * 32768 + p * 1024 + l * 16)
                    = sreg[q];
            }
        }
    };

    // 8 harmonics of (lhalf ? sin : cos)((k+1)x) via Chebyshev recurrence
    auto chain = [&](float xv) -> short8 {
        float s1, c1;
        __sincosf(xv, &s1, &c1);
        float p1 = lhalf ? s1 : c1;
        float p2 = p2init;
        alignas(16) __hip_bfloat16 h[8];
        h[0] = __float2bfloat16(p1);
        const float tc = c1 + c1;
#pragma unroll
        for (int k = 1; k < 8; ++k) {
            const float pn = __builtin_fmaf(tc, p1, -p2);
            p2 = p1; p1 = pn;
            h[k] = __float2bfloat16(pn);
        }
        return *(const short8*)h;
    };

    auto rdB4 = [&](short8* dst, int buf, int ii) {
#pragma unroll
        for (int cf = 0; cf < 4; ++cf)
            dst[cf] = *(const short8*)(bbase + buf * 32768 + ii * 4096
                                       + cf * 1024);
    };

    auto mfma8 = [&](const short8& a0, const short8& a1, const short8* b) {
        __builtin_amdgcn_s_setprio(1);
#pragma unroll
        for (int cf = 0; cf < 4; ++cf) {
            acc0[cf] = __builtin_amdgcn_mfma_f32_32x32x16_bf16(
                a0, b[cf], acc0[cf], 0, 0, 0);
            acc1[cf] = __builtin_amdgcn_mfma_f32_32x32x16_bf16(
                a1, b[cf], acc1[cf], 0, 0, 0);
        }
        __builtin_amdgcn_s_setprio(0);
    };

    // prologue
    stage_issue(0, 0);
    stage_write(0);
    float4 xc0 = *(const float4*)(xp0);
    float4 xc1 = *(const float4*)(xp1);
    __syncthreads();
    short8 afA0 = chain(xc0.x), afA1 = chain(xc1.x);
    short8 afB0, afB1;
    short8 bA[4], bB[4];

#pragma unroll 1
    for (int g = 0; g < NGRP; ++g) {
        const int buf = g & 1;

        if (g + 1 < NGRP) stage_issue(buf ^ 1, g + 1);
        float4 xn0 = xc0, xn1 = xc1;
        if (g + 1 < NGRP) {
            xn0 = *(const float4*)(xp0 + (size_t)(g + 1) * 4);
            xn1 = *(const float4*)(xp1 + (size_t)(g + 1) * 4);
        }

        rdB4(bA, buf, 0);
        // ii=0 (prefetch ii=1)
        rdB4(bB, buf, 1);
        afB0 = chain(xc0.y); afB1 = chain(xc1.y);
        mfma8(afA0, afA1, bA);
        // ii=1 (prefetch ii=2)
        rdB4(bA, buf, 2);
        afA0 = chain(xc0.z); afA1 = chain(xc1.z);
        mfma8(afB0, afB1, bB);
        // ii=2 (prefetch ii=3)
        rdB4(bB, buf, 3);
        afB0 = chain(xc0.w); afB1 = chain(xc1.w);
        mfma8(afA0, afA1, bA);
        // ii=3 (prefetch next group's ii=0 chains)
        afA0 = chain(xn0.x); afA1 = chain(xn1.x);
        mfma8(afB0, afB1, bB);

        if (g + 1 < NGRP) stage_write(buf ^ 1);
        __syncthreads();
        xc0 = xn0; xc1 = xn1;
    }

    // ---- epilogue: combine k-halves through LDS, then store ---------------
#pragma unroll 1
    for (int rnd = 0; rnd < 2; ++rnd) {
        if (kh == 1 && (wm >> 1) == rnd) {
            char* base = (char*)&Blds[0][0] + (wm & 1) * 32768;
#pragma unroll
            for (int m = 0; m < 2; ++m)
#pragma unroll
                for (int cf = 0; cf < 4; ++cf) {
                    const f32x16& a = m ? acc1[cf] : acc0[cf];
#pragma unroll
                    for (int rr = 0; rr < 4; ++rr) {
                        float4 v = { a[rr*4+0], a[rr*4+1], a[rr*4+2], a[rr*4+3] };
                        *(float4*)(base + (size_t)(((m*4+cf)*4+rr)*1024) + l*16) = v;
                    }
                }
        }
        __syncthreads();
        if (kh == 0 && (wm >> 1) == rnd) {
            const char* base = (const char*)&Blds[0][0] + (wm & 1) * 32768;
#pragma unroll
            for (int m = 0; m < 2; ++m)
#pragma unroll
                for (int cf = 0; cf < 4; ++cf) {
                    const f32x16& a = m ? acc1[cf] : acc0[cf];
                    const int ocol = ch * 128 + cf * 32 + lrow;
#pragma unroll
                    for (int rr = 0; rr < 4; ++rr) {
                        float4 v = *(const float4*)(base
                                  + (size_t)(((m*4+cf)*4+rr)*1024) + l*16);
                        const int orow = rb * 256 + wm * 64 + m * 32
                                       + 8 * rr + 4 * lhalf;
                        float* op = out + (size_t)orow * 256 + ocol;
                        op[0]       = a[rr*4+0] + v.x;
                        op[256]     = a[rr*4+1] + v.y;
                        op[512]     = a[rr*4+2] + v.z;
                        op[768]     = a[rr*4+3] + v.w;
                    }
                }
        }
        __syncthreads();
    }
}

extern "C" void kernel_launch(void* const* d_in, const int* in_sizes, int n_in,
                              void* d_out, int out_size, void* d_ws, size_t ws_size,
                              hipStream_t stream) {
    const float* x  = (const float*)d_in[0];
    const float* ca = (const float*)d_in[1];
    const float* cb = (const float*)d_in[2];
    float* out = (float*)d_out;

    const size_t wt_bytes = (size_t)131072 * 16;   // 2 MiB

    if (ws_size >= wt_bytes) {
        unsigned short* wt = (unsigned short*)d_ws;
        pack_w_kernel<<<512, 256, 0, stream>>>(ca, cb, wt);
        kan_gemm<true><<<256, 512, 0, stream>>>(x, wt, ca, cb, out);
    } else {
        kan_gemm<false><<<256, 512, 0, stream>>>(x, nullptr, ca, cb, out);
    }
}